// Round 11
// baseline (258.109 us; speedup 1.0000x reference)
//
#include <hip/hip_runtime.h>

#define HWSZ 65536   // 256*256
#define CCH  64

typedef __bf16 bf16x8 __attribute__((ext_vector_type(8)));
typedef __bf16 bf16x4 __attribute__((ext_vector_type(4)));
typedef float  f32x4  __attribute__((ext_vector_type(4)));

__device__ inline void gload_lds16(const void* g, void* l) {
    __builtin_amdgcn_global_load_lds(
        (const __attribute__((address_space(1))) void*)g,
        (__attribute__((address_space(3))) void*)l, 16, 0, 0);
}

// ===========================================================================
// Device bodies (merged into super-kernels below)
// ===========================================================================

// NCHW f32 -> NHWC bf16
__device__ void cvt_body(int cb, const float* __restrict__ src,
                         __bf16* __restrict__ dst)
{
    int p  = cb * 256 + threadIdx.x;
    int b  = p >> 16, hw = p & 65535;
    const float* sp = src + (((size_t)b * 64) << 16) + hw;
    __bf16* dp = dst + (size_t)p * 64;
    #pragma unroll
    for (int c8 = 0; c8 < 8; ++c8) {
        bf16x8 v8;
        #pragma unroll
        for (int j = 0; j < 8; ++j)
            v8[j] = (__bf16)sp[(size_t)(c8 * 8 + j) << 16];
        *(bf16x8*)(dp + c8 * 8) = v8;
    }
}

// 3x3 W prep: f32 [64][64][9] -> bf16 [ci][9][64 rows][32 ch] linear
__device__ void prep3_body(int cb, const float* __restrict__ src,
                           __bf16* __restrict__ dst)
{
    int t = cb * 256 + threadIdx.x;     // 36864 total, exact
    int ii = t & 31;
    int o  = (t >> 5) & 63;
    int r  = t >> 11;                   // ci*9 + k
    int k  = r % 9, ci = r / 9;
    dst[t] = (__bf16)src[((size_t)o * 64 + ci * 32 + ii) * 9 + k];
}

// fused 5x5 W prep: -> bf16 [ci][25][96 rows][32 ch]; rows 0-63 mt, 64-72 aw
__device__ void prepF_body(int cb, const float* __restrict__ mt,
                           const float* __restrict__ aw, __bf16* __restrict__ dst)
{
    int t = cb * 256 + threadIdx.x;     // 153600 total, exact
    int ii = t & 31;
    int r  = (t >> 5) % 96;
    int q  = t / 3072;                  // ci*25 + k
    int k  = q % 25, ci = q / 25;
    int i  = ci * 32 + ii;
    float v = 0.f;
    if (r < 64)      v = mt[((size_t)r * 64 + i) * 25 + k];
    else if (r < 73) v = aw[((size_t)(r - 64) * 64 + i) * 25 + k];
    dst[t] = (__bf16)v;
}

// ---------------------------------------------------------------------------
// MFMA implicit-GEMM conv, ci-split (K=32 per phase, 2 channel-halves).
// LDS: lx [NPIX][32ch] bf16 (64-B rows, balanced banks), lw dbuf [SROWS][32].
// W staged async (global_load_lds), counted vmcnt, raw barriers.
// ---------------------------------------------------------------------------
template<int KSZ, int MFT, int RELU, int EPI>
__device__ void mconv_body(char* smem, int bx, int by, int b,
    const __bf16* __restrict__ xh, const __bf16* __restrict__ wb,
    const float* __restrict__ bias, const float* __restrict__ bias2,
    float* __restrict__ outf, __bf16* __restrict__ outh,
    float* __restrict__ out2)
{
    constexpr int PAD   = KSZ / 2;
    constexpr int TW    = 16 + 2 * PAD;
    constexpr int NPIX  = TW * TW;
    constexpr int KK    = KSZ * KSZ;
    constexpr int SROWS = (MFT == 5) ? 96 : 64;
    constexpr int SLICE = SROWS * 64;        // bytes per (ci,k) W slice

    __bf16* lx  = (__bf16*)smem;             // NPIX*32
    __bf16* lw0 = lx + NPIX * 32;            // SROWS*32
    __bf16* lw1 = lw0 + SROWS * 32;
    float*  lb  = (float*)(lw1 + SROWS * 32);

    const int t    = threadIdx.x;
    const int w0   = bx * 16, h0 = by * 16;
    const int wvv  = t >> 6;
    const int lane = t & 63;
    const int px   = lane & 15;
    const int g    = lane >> 4;

    auto STAGE = [&](int ci, int k, __bf16* lbuf) {
        const char* gs = (const char*)wb + (size_t)(ci * KK + k) * SLICE;
        if constexpr (MFT == 5) {
            if (wvv < 3) {
                #pragma unroll
                for (int r = 0; r < 2; ++r) {
                    int ub = wvv * 128 + r * 64;
                    gload_lds16(gs + (ub + lane) * 16, (char*)lbuf + ub * 16);
                }
            }
        } else {
            int ub = wvv * 64;
            gload_lds16(gs + (ub + lane) * 16, (char*)lbuf + ub * 16);
        }
    };

    if (t < 64) lb[t] = bias[t];
    if constexpr (MFT == 5) {
        if (t >= 64 && t < 80) lb[t] = (t - 64 < 9) ? bias2[t - 64] : 0.f;
    }

    f32x4 acc[MFT][4];
    #pragma unroll
    for (int m = 0; m < MFT; ++m)
        #pragma unroll
        for (int nf = 0; nf < 4; ++nf)
            acc[m][nf] = (f32x4){0.f, 0.f, 0.f, 0.f};

    for (int ci = 0; ci < 2; ++ci) {
        if (ci) __syncthreads();             // readers of lx/lw done
        STAGE(ci, 0, lw0);
        STAGE(ci, 1, lw1);

        // stage x half-channels: coalesced (8 px * 128B contiguous per wave)
        bf16x8 zv;
        #pragma unroll
        for (int j = 0; j < 8; ++j) zv[j] = (__bf16)0.f;
        for (int e = t; e < NPIX * 4; e += 256) {
            int pix = e >> 2, c4 = e & 3;
            int sy = pix / TW, sx = pix - sy * TW;
            int gy = h0 + sy - PAD, gx = w0 + sx - PAD;
            bool ok = (unsigned)gy < 256u && (unsigned)gx < 256u;
            bf16x8 v8 = zv;
            if (ok) v8 = *(const bf16x8*)(xh + ((((size_t)b << 16) + gy * 256 + gx) << 6)
                                          + ci * 32 + c4 * 8);
            *(bf16x8*)(lx + pix * 32 + c4 * 8) = v8;
        }
        __syncthreads();                     // x half + W slices 0,1 resident

        #pragma unroll
        for (int k = 0; k < KK; ++k) {
            __bf16* lwb = (k & 1) ? lw1 : lw0;
            const int dy = k / KSZ, dx = k - dy * KSZ;

            bf16x8 bfr[4];
            #pragma unroll
            for (int nf = 0; nf < 4; ++nf) {
                int pix = (wvv * 4 + nf + dy) * TW + (px + dx);
                bfr[nf] = *(const bf16x8*)(lx + pix * 32 + g * 8);
            }
            #pragma unroll
            for (int m = 0; m < MFT; ++m) {
                bf16x8 afr = *(const bf16x8*)(lwb + (m * 16 + px) * 32 + g * 8);
                #pragma unroll
                for (int nf = 0; nf < 4; ++nf)
                    acc[m][nf] = __builtin_amdgcn_mfma_f32_16x16x32_bf16(
                        afr, bfr[nf], acc[m][nf], 0, 0, 0);
            }

            if (k == KK - 1) break;

            asm volatile("s_waitcnt lgkmcnt(0)" ::: "memory");
            __builtin_amdgcn_sched_barrier(0);
            __builtin_amdgcn_s_barrier();    // all waves done with lw[k&1]
            bool issued = (k + 2 < KK);
            if (issued) STAGE(ci, k + 2, (k & 1) ? lw1 : lw0);
            if constexpr (MFT == 5) {
                if (issued && wvv < 3) asm volatile("s_waitcnt vmcnt(2)" ::: "memory");
                else                   asm volatile("s_waitcnt vmcnt(0)" ::: "memory");
            } else {
                if (issued) asm volatile("s_waitcnt vmcnt(1)" ::: "memory");
                else        asm volatile("s_waitcnt vmcnt(0)" ::: "memory");
            }
            __builtin_amdgcn_sched_barrier(0);
            __builtin_amdgcn_s_barrier();    // slice k+1 visible
        }
    }

    // ---- epilogue (D row = g*4+j (+16*m), col = px)
    #pragma unroll
    for (int m = 0; m < MFT; ++m) {
        #pragma unroll
        for (int nf = 0; nf < 4; ++nf) {
            int row = h0 + wvv * 4 + nf, col = w0 + px;
            if (m < 4) {
                float vj[4];
                #pragma unroll
                for (int j = 0; j < 4; ++j) {
                    float v = acc[m][nf][j] + lb[m * 16 + g * 4 + j];
                    if (RELU) v = v > 0.f ? v : 0.01f * v;
                    vj[j] = v;
                }
                if constexpr (EPI == 0) {
                    bf16x4 pk;
                    #pragma unroll
                    for (int j = 0; j < 4; ++j) pk[j] = (__bf16)vj[j];
                    *(bf16x4*)(outh + ((((size_t)b << 16) + row * 256 + col) << 6)
                                    + m * 16 + g * 4) = pk;
                } else {
                    #pragma unroll
                    for (int j = 0; j < 4; ++j)
                        outf[((size_t)(b * 64 + m * 16 + g * 4 + j) << 16)
                             + row * 256 + col] = vj[j];
                }
            } else {
                #pragma unroll
                for (int j = 0; j < 4; ++j) {
                    int o2 = g * 4 + j;
                    if (o2 < 9)
                        out2[((size_t)(b * 9 + o2) << 16) + row * 256 + col]
                            = acc[m][nf][j] + lb[64 + o2];
                }
            }
        }
    }
}

// 1x1 conv (residual) from NHWC bf16 x -> f32 NCHW
__device__ void conv1x1_body(char* smem, int cb,
    const __bf16* __restrict__ xh, const float* __restrict__ w,
    const float* __restrict__ bias, float* __restrict__ out)
{
    float* lwT = (float*)smem;    // [i][o] 4096
    float* lb  = lwT + 4096;
    int t = threadIdx.x;
    for (int s = t; s < 4096; s += 256) lwT[s] = w[(s & 63) * 64 + (s >> 6)];
    if (t < 64) lb[t] = bias[t];
    __syncthreads();

    int p  = cb * 256 + t;
    int b  = p >> 16, hw = p & 65535;
    const __bf16* xp = xh + (size_t)p * 64;

    float acc[64];
    #pragma unroll
    for (int o = 0; o < 64; ++o) acc[o] = lb[o];

    #pragma unroll
    for (int c8 = 0; c8 < 8; ++c8) {
        bf16x8 v8 = *(const bf16x8*)(xp + c8 * 8);
        #pragma unroll
        for (int j = 0; j < 8; ++j) {
            float xi = (float)v8[j];
            const float4* w4 = (const float4*)&lwT[(c8 * 8 + j) * 64];
            #pragma unroll
            for (int o4 = 0; o4 < 16; ++o4) {
                float4 wv = w4[o4];
                acc[o4*4+0] += wv.x * xi;
                acc[o4*4+1] += wv.y * xi;
                acc[o4*4+2] += wv.z * xi;
                acc[o4*4+3] += wv.w * xi;
            }
        }
    }
    float* op = out + (((size_t)b * 64) << 16) + hw;
    #pragma unroll
    for (int o = 0; o < 64; ++o) op[(size_t)o << 16] = acc[o];
}

// ===========================================================================
// Kernels
// ===========================================================================

// prep super-kernel: cvt x, cvt mask, all weight preps. Grid 2512.
__global__ __launch_bounds__(256) void k_prep(
    const float* x, const float* mask,
    const float* c1w, const float* c2w,
    const float* mt1w, const float* aw1w,
    const float* mt2w, const float* aw2w,
    __bf16* xh, __bf16* mh,
    __bf16* wbc1, __bf16* wbc2, __bf16* wbF1, __bf16* wbF2)
{
    int bid = blockIdx.x;
    if      (bid < 512)  cvt_body(bid, x, xh);
    else if (bid < 1024) cvt_body(bid - 512, mask, mh);
    else if (bid < 1168) prep3_body(bid - 1024, c1w, wbc1);
    else if (bid < 1312) prep3_body(bid - 1168, c2w, wbc2);
    else if (bid < 1912) prepF_body(bid - 1312, mt1w, aw1w, wbF1);
    else                 prepF_body(bid - 1912, mt2w, aw2w, wbF2);
}

// super1: F1 (fused mt1+aw1, 512 blocks) || c3_1 (512 blocks). Grid 1024.
__global__ __launch_bounds__(256, 4) void k_super1(
    const __bf16* mh, const __bf16* xh,
    const __bf16* wbF1, const __bf16* wbc1,
    const float* mt1_b, const float* aw1_b, const float* c1_b,
    __bf16* maska, float* wgt, __bf16* x1h)
{
    __shared__ __align__(16) char smem[38400];
    int bid = blockIdx.x;
    if (bid < 512) {
        mconv_body<5,5,1,0>(smem, bid & 15, (bid >> 4) & 15, bid >> 8,
                            mh, wbF1, mt1_b, aw1_b, nullptr, maska, wgt);
    } else {
        int r = bid - 512;
        mconv_body<3,4,0,0>(smem, r & 15, (r >> 4) & 15, r >> 8,
                            xh, wbc1, c1_b, nullptr, nullptr, x1h, nullptr);
    }
}

// super2: F2 || c3_2 || conv1x1. Grid 1536.
__global__ __launch_bounds__(256, 4) void k_super2(
    const __bf16* maska, const __bf16* xah, const __bf16* xh,
    const __bf16* wbF2, const __bf16* wbc2,
    const float* mt2_b, const float* aw2_b, const float* c2_b,
    const float* crw, const float* crb,
    float* outm, float* wgt, __bf16* x2h, float* outx)
{
    __shared__ __align__(16) char smem[38400];
    int bid = blockIdx.x;
    if (bid < 512) {
        mconv_body<5,5,1,1>(smem, bid & 15, (bid >> 4) & 15, bid >> 8,
                            maska, wbF2, mt2_b, aw2_b, outm, nullptr, wgt);
    } else if (bid < 1024) {
        int r = bid - 512;
        mconv_body<3,4,0,0>(smem, r & 15, (r >> 4) & 15, r >> 8,
                            xah, wbc2, c2_b, nullptr, nullptr, x2h, nullptr);
    } else {
        conv1x1_body(smem, bid - 1024, xh, crw, crb, outx);
    }
}

// Adaptive einsum, coalesced: 8 threads/pixel. -> bf16 NHWC.
__global__ __launch_bounds__(256, 4) void k_ada1(
    const float* __restrict__ wgt, const __bf16* __restrict__ xin,
    __bf16* __restrict__ outh)
{
    int t  = threadIdx.x;
    int pg = t >> 3, c8 = t & 7;
    int p  = blockIdx.x * 32 + pg;
    int b  = p >> 16, hw = p & 65535;
    int h  = hw >> 8, wc = hw & 255;

    const float* wp = wgt + ((size_t)(b * 9) << 16) + hw;
    const __bf16* cen = xin + (size_t)p * 64 + c8 * 8;

    float wk[9];
    const __bf16* nbp[9];
    #pragma unroll
    for (int dy = 0; dy < 3; ++dy)
        #pragma unroll
        for (int dx = 0; dx < 3; ++dx) {
            int k = dy * 3 + dx;
            bool ok = ((unsigned)(h + dy - 1) < 256u) &&
                      ((unsigned)(wc + dx - 1) < 256u);
            wk[k]  = ok ? wp[(size_t)k << 16] : 0.f;
            nbp[k] = ok ? cen + ((dy - 1) * 256 + (dx - 1)) * 64 : cen;
        }

    float acc[8] = {0.f,0.f,0.f,0.f,0.f,0.f,0.f,0.f};
    #pragma unroll
    for (int k = 0; k < 9; ++k) {
        bf16x8 v8 = *(const bf16x8*)nbp[k];
        float w = wk[k];
        #pragma unroll
        for (int j = 0; j < 8; ++j) acc[j] += w * (float)v8[j];
    }

    bf16x8 o8;
    #pragma unroll
    for (int j = 0; j < 8; ++j) {
        float v = acc[j];
        o8[j] = (__bf16)(v > 0.f ? v : 0.01f * v);
    }
    *(bf16x8*)(outh + (size_t)p * 64 + c8 * 8) = o8;
}

// Final adaptive einsum + RMW residual add (f32 NCHW via LDS transpose).
__global__ __launch_bounds__(256, 4) void k_ada2(
    const float* __restrict__ wgt, const __bf16* __restrict__ x2h,
    float* __restrict__ outf)
{
    __shared__ float ls[32 * 65];

    int t  = threadIdx.x;
    int pg = t >> 3, c8 = t & 7;
    int p  = blockIdx.x * 32 + pg;
    int b  = p >> 16, hw = p & 65535;
    int h  = hw >> 8, wc = hw & 255;

    const float* wp = wgt + ((size_t)(b * 9) << 16) + hw;
    const __bf16* cen = x2h + (size_t)p * 64 + c8 * 8;

    float wk[9];
    const __bf16* nbp[9];
    #pragma unroll
    for (int dy = 0; dy < 3; ++dy)
        #pragma unroll
        for (int dx = 0; dx < 3; ++dx) {
            int k = dy * 3 + dx;
            bool ok = ((unsigned)(h + dy - 1) < 256u) &&
                      ((unsigned)(wc + dx - 1) < 256u);
            wk[k]  = ok ? wp[(size_t)k << 16] : 0.f;
            nbp[k] = ok ? cen + ((dy - 1) * 256 + (dx - 1)) * 64 : cen;
        }

    float acc[8] = {0.f,0.f,0.f,0.f,0.f,0.f,0.f,0.f};
    #pragma unroll
    for (int k = 0; k < 9; ++k) {
        bf16x8 v8 = *(const bf16x8*)nbp[k];
        float w = wk[k];
        #pragma unroll
        for (int j = 0; j < 8; ++j) acc[j] += w * (float)v8[j];
    }

    #pragma unroll
    for (int j = 0; j < 8; ++j) {
        float v = acc[j];
        ls[pg * 65 + c8 * 8 + j] = v > 0.f ? v : 0.01f * v;
    }
    __syncthreads();

    int pbase = blockIdx.x * 32;
    int bb    = pbase >> 16, hwb = pbase & 65535;
    int pix   = t & 31, cq = t >> 5;
    #pragma unroll
    for (int i = 0; i < 8; ++i) {
        int c = i * 8 + cq;
        float v = ls[pix * 65 + c];
        float* op = outf + ((size_t)(bb * 64 + c) << 16) + hwb + pix;
        *op = *op + v;
    }
}

// ---------------------------------------------------------------------------
// Buffer plan (ws use = 72,589,312 B; ws_size ~ 256 MiB per fillBuffer evidence):
//   wgt   f32  @0           4,718,592   adaptive weights (F1->ada1, F2->ada2)
//   xh    bf16 @4,718,592  16,777,216   x NHWC (live whole call)
//   mh    bf16 @21,495,808 16,777,216   mask NHWC (dead after super1; x2h reuses)
//   wb    bf16 @38,273,024    761,856   prepped conv weights (ci-split layout)
//   maska bf16 @39,034,880 16,777,216   F1 out, F2 in (ws: avoids super2 race)
//   xah   bf16 @55,812,096 16,777,216   ada1 out, c3_2 in (ws: avoids race)
//   x1h   = out_m scratch (c3_1 out, ada1 in; F2 overwrites out_m later)
// Launches: prep -> super1(F1||c3_1) -> ada1 -> super2(F2||c3_2||conv1x1) -> ada2
// ---------------------------------------------------------------------------
extern "C" void kernel_launch(void* const* d_in, const int* in_sizes, int n_in,
                              void* d_out, int out_size, void* d_ws, size_t ws_size,
                              hipStream_t stream)
{
    const float* x     = (const float*)d_in[0];
    const float* mask  = (const float*)d_in[1];
    const float* aw1_w = (const float*)d_in[2];
    const float* aw1_b = (const float*)d_in[3];
    const float* mt1_w = (const float*)d_in[4];
    const float* mt1_b = (const float*)d_in[5];
    const float* c1_w  = (const float*)d_in[6];
    const float* c1_b  = (const float*)d_in[7];
    const float* aw2_w = (const float*)d_in[8];
    const float* aw2_b = (const float*)d_in[9];
    const float* mt2_w = (const float*)d_in[10];
    const float* mt2_b = (const float*)d_in[11];
    const float* c2_w  = (const float*)d_in[12];
    const float* c2_b  = (const float*)d_in[13];
    const float* cr_w  = (const float*)d_in[14];
    const float* cr_b  = (const float*)d_in[15];

    float* out_x = (float*)d_out;
    float* out_m = (float*)d_out + 8388608;

    float*  wgt   = (float*)d_ws;
    __bf16* xh    = (__bf16*)((char*)d_ws + 4718592);
    __bf16* mh    = (__bf16*)((char*)d_ws + 21495808);
    __bf16* x2h   = mh;                                // sequential live ranges
    __bf16* wbase = (__bf16*)((char*)d_ws + 38273024);
    __bf16* wb_c1 = wbase;             // 36864 elems
    __bf16* wb_c2 = wbase + 36864;     // 36864
    __bf16* wb_F1 = wbase + 73728;     // 153600
    __bf16* wb_F2 = wbase + 227328;    // 153600
    __bf16* maska = (__bf16*)((char*)d_ws + 39034880);
    __bf16* xah   = (__bf16*)((char*)d_ws + 55812096);
    __bf16* x1h   = (__bf16*)out_m;                    // scratch until F2

    dim3 blk(256);

    // 1. prep: layout conversions + weight preps (one launch)
    k_prep<<<dim3(2512), blk, 0, stream>>>(x, mask, c1_w, c2_w,
        mt1_w, aw1_w, mt2_w, aw2_w, xh, mh, wb_c1, wb_c2, wb_F1, wb_F2);

    // 2. super1: F1(mh)->maska,wgt  ||  c3_1(xh)->x1h
    k_super1<<<dim3(1024), blk, 0, stream>>>(mh, xh, wb_F1, wb_c1,
        mt1_b, aw1_b, c1_b, maska, wgt, x1h);

    // 3. xa = lrelu(ada(wgt, x1)) -> xah
    k_ada1<<<dim3(4096), blk, 0, stream>>>(wgt, x1h, xah);

    // 4. super2: F2(maska)->out_m,wgt || c3_2(xah)->x2h || conv1x1(xh)->out_x
    k_super2<<<dim3(1536), blk, 0, stream>>>(maska, xah, xh, wb_F2, wb_c2,
        mt2_b, aw2_b, c2_b, cr_w, cr_b, out_m, wgt, x2h, out_x);

    // 5. out_x += lrelu(ada(wgt, x2))
    k_ada2<<<dim3(4096), blk, 0, stream>>>(wgt, x2h, out_x);
}

// Round 12
// 193.092 us; speedup vs baseline: 1.3367x; 1.3367x over previous
//
#include <hip/hip_runtime.h>

#define HWSZ 65536   // 256*256
#define CCH  64

typedef __bf16 bf16x8 __attribute__((ext_vector_type(8)));
typedef __bf16 bf16x4 __attribute__((ext_vector_type(4)));
typedef float  f32x4  __attribute__((ext_vector_type(4)));

__device__ inline void gload_lds16(const void* g, void* l) {
    __builtin_amdgcn_global_load_lds(
        (const __attribute__((address_space(1))) void*)g,
        (__attribute__((address_space(3))) void*)l, 16, 0, 0);
}

// ===========================================================================
// Prep bodies, merged into one launch (independent, tiny register use)
// ===========================================================================

// NCHW f32 -> NHWC bf16
__device__ void cvt_body(int cb, const float* __restrict__ src,
                         __bf16* __restrict__ dst)
{
    int p  = cb * 256 + threadIdx.x;
    int b  = p >> 16, hw = p & 65535;
    const float* sp = src + (((size_t)b * 64) << 16) + hw;
    __bf16* dp = dst + (size_t)p * 64;
    #pragma unroll
    for (int c8 = 0; c8 < 8; ++c8) {
        bf16x8 v8;
        #pragma unroll
        for (int j = 0; j < 8; ++j)
            v8[j] = (__bf16)sp[(size_t)(c8 * 8 + j) << 16];
        *(bf16x8*)(dp + c8 * 8) = v8;
    }
}

// 3x3 W prep: f32 [64][64][9] -> bf16 [9][64 rows][64], inverse-swizzled
__device__ void prep3_body(int cb, const float* __restrict__ src,
                           __bf16* __restrict__ dst)
{
    int t = cb * 256 + threadIdx.x;
    if (t >= 9 * 64 * 64) return;
    int j = t & 7;
    int u = (t >> 3) % 512;
    int k = t / 4096;
    int o = u >> 3;
    int s = (u & 7) ^ (o & 7);
    int i = s * 8 + j;
    dst[t] = (__bf16)src[((size_t)o * 64 + i) * 9 + k];
}

// fused 5x5 W prep: [25][96 rows][64]; rows 0-63 mt, 64-72 aw, 73-95 zero
__device__ void prepF_body(int cb, const float* __restrict__ mt,
                           const float* __restrict__ aw, __bf16* __restrict__ dst)
{
    int t = cb * 256 + threadIdx.x;
    if (t >= 25 * 96 * 64) return;
    int j = t & 7;
    int u = (t >> 3) % 768;
    int k = t / 6144;
    int r = u >> 3;
    int s = (u & 7) ^ (r & 7);
    int i = s * 8 + j;
    float v = 0.f;
    if (r < 64)      v = mt[((size_t)r * 64 + i) * 25 + k];
    else if (r < 73) v = aw[((size_t)(r - 64) * 64 + i) * 25 + k];
    dst[t] = (__bf16)v;
}

// prep super-kernel. Grid 2512.
__global__ __launch_bounds__(256) void k_prep(
    const float* x, const float* mask,
    const float* c1w, const float* c2w,
    const float* mt1w, const float* aw1w,
    const float* mt2w, const float* aw2w,
    __bf16* xh, __bf16* mh,
    __bf16* wbc1, __bf16* wbc2, __bf16* wbF1, __bf16* wbF2)
{
    int bid = blockIdx.x;
    if      (bid < 512)  cvt_body(bid, x, xh);
    else if (bid < 1024) cvt_body(bid - 512, mask, mh);
    else if (bid < 1168) prep3_body(bid - 1024, c1w, wbc1);
    else if (bid < 1312) prep3_body(bid - 1168, c2w, wbc2);
    else if (bid < 1912) prepF_body(bid - 1312, mt1w, aw1w, wbF1);
    else                 prepF_body(bid - 1912, mt2w, aw2w, wbF2);
}

// ---------------------------------------------------------------------------
// MFMA implicit-GEMM conv, NHWC bf16 input (round-10 proven structure +
// T5 setprio around the MFMA cluster). Block = 16x16 pixel tile, 4 waves.
// MFT=4: 64 out-ch. MFT=5: fused 64 mt + 9 aw (aw -> out2, f32 NCHW).
// EPI=0: main out bf16 NHWC; EPI=1: f32 NCHW.
// ---------------------------------------------------------------------------
template<int KSZ, int MFT, int RELU, int EPI>
__global__ __launch_bounds__(256) void k_mconv(
    const __bf16* __restrict__ xh, const __bf16* __restrict__ wb,
    const float* __restrict__ bias, const float* __restrict__ bias2,
    float* __restrict__ outf, __bf16* __restrict__ outh,
    float* __restrict__ out2)
{
    constexpr int PAD   = KSZ / 2;
    constexpr int TW    = 16 + 2 * PAD;
    constexpr int NPIX  = TW * TW;
    constexpr int KK    = KSZ * KSZ;
    constexpr int SROWS = (MFT == 5) ? 96 : 64;
    constexpr int SLICE = SROWS * 128;
    constexpr int NISS  = SROWS / 32;

    __shared__ __align__(16) __bf16 lx[NPIX * 64];
    __shared__ __align__(16) __bf16 lw[2][SROWS * 64];
    __shared__ float lb[80];

    const int t    = threadIdx.x;
    const int w0   = blockIdx.x * 16, h0 = blockIdx.y * 16, b = blockIdx.z;
    const int wvv  = t >> 6;
    const int lane = t & 63;
    const int px   = lane & 15;
    const int g    = lane >> 4;

    auto STAGE = [&](int k, int buf) {
        const char* gs = (const char*)wb + (size_t)k * SLICE;
        char* lbase = (char*)lw[buf];
        #pragma unroll
        for (int r = 0; r < NISS; ++r) {
            int ub = (wvv * NISS + r) * 64;
            gload_lds16(gs + (ub + lane) * 16, lbase + ub * 16);
        }
    };

    STAGE(0, 0);
    STAGE(1, 1);

    if (t < 64) lb[t] = bias[t];
    if constexpr (MFT == 5) {
        if (t >= 64 && t < 80) lb[t] = (t - 64 < 9) ? bias2[t - 64] : 0.f;
    }

    // ---- stage x tile from NHWC bf16
    bf16x8 zv;
    #pragma unroll
    for (int j = 0; j < 8; ++j) zv[j] = (__bf16)0.f;
    constexpr int PITER = (NPIX + 255) / 256;
    #pragma unroll
    for (int pi = 0; pi < PITER; ++pi) {
        int pix = pi * 256 + t;
        if (pix < NPIX) {
            int sy = pix / TW, sx = pix - sy * TW;
            int gy = h0 + sy - PAD, gx = w0 + sx - PAD;
            bool ok = (unsigned)gy < 256u && (unsigned)gx < 256u;
            const __bf16* src = xh + ((((size_t)b << 16) + gy * 256 + gx) << 6);
            int rowbase = pix << 7, sw = (pix & 7) << 4;
            #pragma unroll
            for (int c8 = 0; c8 < 8; ++c8) {
                bf16x8 v8 = ok ? *(const bf16x8*)(src + c8 * 8) : zv;
                *(bf16x8*)((char*)lx + rowbase + ((c8 << 4) ^ sw)) = v8;
            }
        }
    }
    __syncthreads();   // full drain once: x, lb, W slices 0 & 1 resident

    f32x4 acc[MFT][4];
    #pragma unroll
    for (int m = 0; m < MFT; ++m)
        #pragma unroll
        for (int nf = 0; nf < 4; ++nf)
            acc[m][nf] = (f32x4){0.f, 0.f, 0.f, 0.f};

    #pragma unroll
    for (int k = 0; k < KK; ++k) {
        const __bf16* lwb = lw[k & 1];
        const int dy = k / KSZ, dx = k - dy * KSZ;

        bf16x8 bfr[4][2];
        #pragma unroll
        for (int nf = 0; nf < 4; ++nf) {
            int pix = (wvv * 4 + nf + dy) * TW + (px + dx);
            int rowbase = pix << 7, sw = (pix & 7) << 4;
            #pragma unroll
            for (int ks = 0; ks < 2; ++ks)
                bfr[nf][ks] = *(const bf16x8*)((const char*)lx + rowbase + ((((ks * 4 + g) << 4)) ^ sw));
        }
        bf16x8 afr[MFT][2];
        #pragma unroll
        for (int m = 0; m < MFT; ++m) {
            int o = m * 16 + px;
            int rowbase = o << 7, sw = (o & 7) << 4;
            #pragma unroll
            for (int ks = 0; ks < 2; ++ks)
                afr[m][ks] = *(const bf16x8*)((const char*)lwb + rowbase + ((((ks * 4 + g) << 4)) ^ sw));
        }
        __builtin_amdgcn_s_setprio(1);
        #pragma unroll
        for (int m = 0; m < MFT; ++m)
            #pragma unroll
            for (int nf = 0; nf < 4; ++nf)
                #pragma unroll
                for (int ks = 0; ks < 2; ++ks)
                    acc[m][nf] = __builtin_amdgcn_mfma_f32_16x16x32_bf16(
                        afr[m][ks], bfr[nf][ks], acc[m][nf], 0, 0, 0);
        __builtin_amdgcn_s_setprio(0);

        if (k == KK - 1) break;

        asm volatile("s_waitcnt lgkmcnt(0)" ::: "memory");
        __builtin_amdgcn_sched_barrier(0);
        __builtin_amdgcn_s_barrier();            // all waves done with lw[k&1]
        bool issued = (k + 2 < KK);
        if (issued) {
            STAGE(k + 2, k & 1);
            if constexpr (NISS == 2) asm volatile("s_waitcnt vmcnt(2)" ::: "memory");
            else                     asm volatile("s_waitcnt vmcnt(3)" ::: "memory");
        } else {
            asm volatile("s_waitcnt vmcnt(0)" ::: "memory");
        }
        __builtin_amdgcn_sched_barrier(0);
        __builtin_amdgcn_s_barrier();            // slice k+1 visible
    }

    // ---- epilogue
    #pragma unroll
    for (int m = 0; m < MFT; ++m) {
        #pragma unroll
        for (int nf = 0; nf < 4; ++nf) {
            int row = h0 + wvv * 4 + nf, col = w0 + px;
            if (m < 4) {
                float vj[4];
                #pragma unroll
                for (int j = 0; j < 4; ++j) {
                    float v = acc[m][nf][j] + lb[m * 16 + g * 4 + j];
                    if (RELU) v = v > 0.f ? v : 0.01f * v;
                    vj[j] = v;
                }
                if constexpr (EPI == 0) {
                    bf16x4 pk;
                    #pragma unroll
                    for (int j = 0; j < 4; ++j) pk[j] = (__bf16)vj[j];
                    *(bf16x4*)(outh + ((((size_t)b << 16) + row * 256 + col) << 6)
                                    + m * 16 + g * 4) = pk;
                } else {
                    #pragma unroll
                    for (int j = 0; j < 4; ++j)
                        outf[((size_t)(b * 64 + m * 16 + g * 4 + j) << 16)
                             + row * 256 + col] = vj[j];
                }
            } else {
                #pragma unroll
                for (int j = 0; j < 4; ++j) {
                    int o2 = g * 4 + j;
                    if (o2 < 9)
                        out2[((size_t)(b * 9 + o2) << 16) + row * 256 + col]
                            = acc[m][nf][j] + lb[64 + o2];
                }
            }
        }
    }
}

// ---------------------------------------------------------------------------
// 1x1 conv (residual) from NHWC bf16 x. Writes f32 NCHW.
// ---------------------------------------------------------------------------
__global__ __launch_bounds__(256) void k_conv1x1(
    const __bf16* __restrict__ xh, const float* __restrict__ w,
    const float* __restrict__ bias, float* __restrict__ out)
{
    __shared__ __align__(16) float lwT[4096];   // [i][o]
    __shared__ float lb[64];
    int t = threadIdx.x;
    for (int s = t; s < 4096; s += 256) lwT[s] = w[(s & 63) * 64 + (s >> 6)];
    if (t < 64) lb[t] = bias[t];
    __syncthreads();

    int p  = blockIdx.x * 256 + t;
    int b  = p >> 16, hw = p & 65535;
    const __bf16* xp = xh + (size_t)p * 64;

    float acc[64];
    #pragma unroll
    for (int o = 0; o < 64; ++o) acc[o] = lb[o];

    #pragma unroll
    for (int c8 = 0; c8 < 8; ++c8) {
        bf16x8 v8 = *(const bf16x8*)(xp + c8 * 8);
        #pragma unroll
        for (int j = 0; j < 8; ++j) {
            float xi = (float)v8[j];
            const float4* w4 = (const float4*)&lwT[(c8 * 8 + j) * 64];
            #pragma unroll
            for (int o4 = 0; o4 < 16; ++o4) {
                float4 wv = w4[o4];
                acc[o4*4+0] += wv.x * xi;
                acc[o4*4+1] += wv.y * xi;
                acc[o4*4+2] += wv.z * xi;
                acc[o4*4+3] += wv.w * xi;
            }
        }
    }
    float* op = out + (((size_t)b * 64) << 16) + hw;
    #pragma unroll
    for (int o = 0; o < 64; ++o) op[(size_t)o << 16] = acc[o];
}

// ---------------------------------------------------------------------------
// Adaptive einsum, coalesced: 8 threads/pixel, wave = 8 consecutive pixels
// (1KB contiguous per neighbor-load instruction). -> bf16 NHWC.
// ---------------------------------------------------------------------------
__global__ __launch_bounds__(256, 4) void k_ada1(
    const float* __restrict__ wgt, const __bf16* __restrict__ xin,
    __bf16* __restrict__ outh)
{
    int t  = threadIdx.x;
    int pg = t >> 3, c8 = t & 7;
    int p  = blockIdx.x * 32 + pg;
    int b  = p >> 16, hw = p & 65535;
    int h  = hw >> 8, wc = hw & 255;

    const float* wp = wgt + ((size_t)(b * 9) << 16) + hw;
    const __bf16* cen = xin + (size_t)p * 64 + c8 * 8;

    float wk[9];
    const __bf16* nbp[9];
    #pragma unroll
    for (int dy = 0; dy < 3; ++dy)
        #pragma unroll
        for (int dx = 0; dx < 3; ++dx) {
            int k = dy * 3 + dx;
            bool ok = ((unsigned)(h + dy - 1) < 256u) &&
                      ((unsigned)(wc + dx - 1) < 256u);
            wk[k]  = ok ? wp[(size_t)k << 16] : 0.f;
            nbp[k] = ok ? cen + ((dy - 1) * 256 + (dx - 1)) * 64 : cen;
        }

    float acc[8] = {0.f,0.f,0.f,0.f,0.f,0.f,0.f,0.f};
    #pragma unroll
    for (int k = 0; k < 9; ++k) {
        bf16x8 v8 = *(const bf16x8*)nbp[k];
        float w = wk[k];
        #pragma unroll
        for (int j = 0; j < 8; ++j) acc[j] += w * (float)v8[j];
    }

    bf16x8 o8;
    #pragma unroll
    for (int j = 0; j < 8; ++j) {
        float v = acc[j];
        o8[j] = (__bf16)(v > 0.f ? v : 0.01f * v);
    }
    *(bf16x8*)(outh + (size_t)p * 64 + c8 * 8) = o8;
}

// ---------------------------------------------------------------------------
// Final adaptive einsum + RMW residual add (f32 NCHW via LDS transpose).
// ---------------------------------------------------------------------------
__global__ __launch_bounds__(256, 4) void k_ada2(
    const float* __restrict__ wgt, const __bf16* __restrict__ x2h,
    float* __restrict__ outf)
{
    __shared__ float ls[32 * 65];

    int t  = threadIdx.x;
    int pg = t >> 3, c8 = t & 7;
    int p  = blockIdx.x * 32 + pg;
    int b  = p >> 16, hw = p & 65535;
    int h  = hw >> 8, wc = hw & 255;

    const float* wp = wgt + ((size_t)(b * 9) << 16) + hw;
    const __bf16* cen = x2h + (size_t)p * 64 + c8 * 8;

    float wk[9];
    const __bf16* nbp[9];
    #pragma unroll
    for (int dy = 0; dy < 3; ++dy)
        #pragma unroll
        for (int dx = 0; dx < 3; ++dx) {
            int k = dy * 3 + dx;
            bool ok = ((unsigned)(h + dy - 1) < 256u) &&
                      ((unsigned)(wc + dx - 1) < 256u);
            wk[k]  = ok ? wp[(size_t)k << 16] : 0.f;
            nbp[k] = ok ? cen + ((dy - 1) * 256 + (dx - 1)) * 64 : cen;
        }

    float acc[8] = {0.f,0.f,0.f,0.f,0.f,0.f,0.f,0.f};
    #pragma unroll
    for (int k = 0; k < 9; ++k) {
        bf16x8 v8 = *(const bf16x8*)nbp[k];
        float w = wk[k];
        #pragma unroll
        for (int j = 0; j < 8; ++j) acc[j] += w * (float)v8[j];
    }

    #pragma unroll
    for (int j = 0; j < 8; ++j) {
        float v = acc[j];
        ls[pg * 65 + c8 * 8 + j] = v > 0.f ? v : 0.01f * v;
    }
    __syncthreads();

    int pbase = blockIdx.x * 32;
    int bb    = pbase >> 16, hwb = pbase & 65535;
    int pix   = t & 31, cq = t >> 5;
    #pragma unroll
    for (int i = 0; i < 8; ++i) {
        int c = i * 8 + cq;
        float v = ls[pix * 65 + c];
        float* op = outf + ((size_t)(bb * 64 + c) << 16) + hwb + pix;
        *op = *op + v;
    }
}

// ---------------------------------------------------------------------------
// Buffer plan (ws use = 39,034,880 B):
//   wgt  f32  @0           4,718,592   adaptive weights (F1->ada1, F2->ada2)
//   xh   bf16 @4,718,592  16,777,216   x NHWC (live whole call)
//   mh / x2h  @21,495,808 16,777,216   mask NHWC (dead after F1), then x2
//   wb   bf16 @38,273,024    761,856   prepped conv weights
// d_out scratch: out_x lower = maska_h, out_x upper = xa_h, out_m = x1_h.
// Launches: prep -> F1 -> c3_1 -> ada1 -> F2 -> c3_2 -> conv1x1 -> ada2.
// ---------------------------------------------------------------------------
extern "C" void kernel_launch(void* const* d_in, const int* in_sizes, int n_in,
                              void* d_out, int out_size, void* d_ws, size_t ws_size,
                              hipStream_t stream)
{
    const float* x     = (const float*)d_in[0];
    const float* mask  = (const float*)d_in[1];
    const float* aw1_w = (const float*)d_in[2];
    const float* aw1_b = (const float*)d_in[3];
    const float* mt1_w = (const float*)d_in[4];
    const float* mt1_b = (const float*)d_in[5];
    const float* c1_w  = (const float*)d_in[6];
    const float* c1_b  = (const float*)d_in[7];
    const float* aw2_w = (const float*)d_in[8];
    const float* aw2_b = (const float*)d_in[9];
    const float* mt2_w = (const float*)d_in[10];
    const float* mt2_b = (const float*)d_in[11];
    const float* c2_w  = (const float*)d_in[12];
    const float* c2_b  = (const float*)d_in[13];
    const float* cr_w  = (const float*)d_in[14];
    const float* cr_b  = (const float*)d_in[15];

    float* out_x = (float*)d_out;
    float* out_m = (float*)d_out + 8388608;

    float*  wgt   = (float*)d_ws;
    __bf16* xh    = (__bf16*)((char*)d_ws + 4718592);
    __bf16* mh    = (__bf16*)((char*)d_ws + 21495808);
    __bf16* x2h   = mh;                                // sequential live ranges
    __bf16* wbase = (__bf16*)((char*)d_ws + 38273024);
    __bf16* wb_c1 = wbase;             // 36864 elems
    __bf16* wb_c2 = wbase + 36864;     // 36864
    __bf16* wb_F1 = wbase + 73728;     // 153600
    __bf16* wb_F2 = wbase + 227328;    // 153600

    __bf16* maska_h = (__bf16*)out_x;               // lower 16.78 MB
    __bf16* xa_h    = (__bf16*)out_x + 8388608;     // upper 16.78 MB
    __bf16* x1_h    = (__bf16*)out_m;               // lower 16.78 MB

    dim3 blk(256);
    dim3 gconv(16, 16, 2);
    dim3 gpix(512);
    dim3 gada(4096);

    // 0. merged prep: layout conversions + weight preps (one launch)
    k_prep<<<dim3(2512), blk, 0, stream>>>(x, mask, c1_w, c2_w,
        mt1_w, aw1_w, mt2_w, aw2_w, xh, mh, wb_c1, wb_c2, wb_F1, wb_F2);

    // 1. F1(mh): maska = lrelu(mt1) -> maska_h (bf16), weight1 = aw1 -> wgt
    k_mconv<5,5,1,0><<<gconv, blk, 0, stream>>>(mh, wb_F1, mt1_b, aw1_b,
                                                nullptr, maska_h, wgt);
    // 2. x1 = conv3x3(xh, c1) -> x1_h (bf16, out_m scratch)
    k_mconv<3,4,0,0><<<gconv, blk, 0, stream>>>(xh, wb_c1, c1_b, nullptr,
                                                nullptr, x1_h, nullptr);
    // 3. xa = lrelu(ada(wgt, x1)) -> xa_h (bf16, out_x upper scratch)
    k_ada1<<<gada, blk, 0, stream>>>(wgt, x1_h, xa_h);
    // 4. F2(maska_h): final mask = lrelu(mt2) -> out_m (f32), weight2 -> wgt
    k_mconv<5,5,1,1><<<gconv, blk, 0, stream>>>(maska_h, wb_F2, mt2_b, aw2_b,
                                                out_m, nullptr, wgt);
    // 5. x2 = conv3x3(xa_h, c2) -> x2h (bf16, ws)
    k_mconv<3,4,0,0><<<gconv, blk, 0, stream>>>(xa_h, wb_c2, c2_b, nullptr,
                                                nullptr, x2h, nullptr);
    // 6. res = conv1x1(xh) -> out_x (f32, clobbers dead scratch)
    k_conv1x1<<<gpix, blk, 0, stream>>>(xh, cr_w, cr_b, out_x);
    // 7. out_x += lrelu(ada(wgt, x2))   (coalesced RMW)
    k_ada2<<<gada, blk, 0, stream>>>(wgt, x2h, out_x);
}